// Round 5
// baseline (1242.339 us; speedup 1.0000x reference)
//
#include <hip/hip_runtime.h>
#include <hip/hip_bf16.h>

// ---------------------------------------------------------------------------
// Nystromformer attention. bf16x3-split 32x32x16 MFMA GEMMs with in-kernel
// fp32->hi/lo conversion for A operands (conflict-free slot-aligned staging);
// weights pre-packed.
// B=4, L=4096, D=1024, H=16, HD=64, NL=64, SEG=64, INV_ITERS=6
// ---------------------------------------------------------------------------

static constexpr int Bn  = 4;
static constexpr int Ln  = 4096;
static constexpr int Dn  = 1024;
static constexpr int Hn  = 16;
static constexpr int HDn = 64;
static constexpr int NLn = 64;
static constexpr int SEGn = 64;
static constexpr int BHn = Bn * Hn;     // 64
static constexpr int Mn  = Bn * Ln;     // 16384
static constexpr int NCH = 8;           // s3v chunks
#define NEG_BIG (-100000.0f)

// ---- workspace offsets (floats). END = 55115840 fl = 210.3 MB -----------
static constexpr size_t OFF_KT  = 0;          // Kt fp32; later attn fp32 (alias)
static constexpr size_t OFF_QT  = 16777216;
static constexpr size_t OFF_VT  = 33554432;   // Vt fp32; later woh/wol packed
static constexpr size_t OFF_WOH = 33554432;   // 524288 fl (alias Vt, packed after s3v)
static constexpr size_t OFF_WOL = 34078720;   // 524288 fl
static constexpr size_t OFF_WH  = 50331648;   // wkqv hi packed, 1572864 fl
static constexpr size_t OFF_WL  = 51904512;   // 1572864 fl
static constexpr size_t OFF_PO  = 50331648;   // Opart [64][8][4096] = 2097152 fl (alias wh/wl)
static constexpr size_t OFF_QLM = 53477376;   // 262144
static constexpr size_t OFF_KLM = 53739520;
static constexpr size_t OFF_S2  = 54001664;
static constexpr size_t OFF_Z   = 54263808;
static constexpr size_t OFF_S3V = 54525952;
static constexpr size_t OFF_WM  = 54788096;
static constexpr size_t OFF_PM  = 55050240;   // 32768
static constexpr size_t OFF_PS  = 55083008;   // 32768
static constexpr size_t OFF_GM  = 55115776;   // 64

using bf16x8 = __attribute__((ext_vector_type(8))) short;
using f32x16 = __attribute__((ext_vector_type(16))) float;

__device__ __forceinline__ unsigned short f2bf(float f) {
    unsigned int u = __float_as_uint(f);
    return (unsigned short)((u + 0x7fffu + ((u >> 16) & 1u)) >> 16);
}
__device__ __forceinline__ float bf2f(unsigned short h) {
    return __uint_as_float((unsigned int)h << 16);
}
// 8 fp32 -> hi bf16x8 (truncated) + lo bf16x8 (rounded residual)
__device__ __forceinline__ void cvt8(const float4 a, const float4 b,
                                     bf16x8& hv, bf16x8& lv) {
    const float f0 = a.x, f1 = a.y, f2 = a.z, f3 = a.w;
    const float f4 = b.x, f5 = b.y, f6 = b.z, f7 = b.w;
    const float fs[8] = {f0, f1, f2, f3, f4, f5, f6, f7};
    #pragma unroll
    for (int e = 0; e < 8; ++e) {
        const unsigned int u = __float_as_uint(fs[e]);
        const unsigned short h = (unsigned short)(u >> 16);
        hv[e] = (short)h;
        lv[e] = (short)f2bf(fs[e] - bf2f(h));
    }
}

// ---------------------------------------------------------------------------
// Weight pack: fp32 [rows][1024] -> hi/lo bf16 in 32x32x16-fragment-ordered
// 128x32 tiles. Tile (rt,kt), slot s = (g*2+kk)*64 + l holds
// row = g*32 + (l&31), k = kk*16 + ((l>>5)&1)*8 + e.
// ---------------------------------------------------------------------------
__global__ __launch_bounds__(256) void k_pack(
    const float* __restrict__ src, unsigned short* __restrict__ dh,
    unsigned short* __restrict__ dl)
{
    __shared__ float Ls[128][33];
    const int rt = blockIdx.x, kt = blockIdx.y;   // kt 0..31
    const int tid = threadIdx.x;
    #pragma unroll
    for (int p = 0; p < 4; ++p) {
        const int row = p * 32 + (tid >> 3);
        const int c4 = (tid & 7) * 4;
        const float4 v = *(const float4*)&src[(size_t)(rt * 128 + row) * 1024 + kt * 32 + c4];
        Ls[row][c4 + 0] = v.x; Ls[row][c4 + 1] = v.y;
        Ls[row][c4 + 2] = v.z; Ls[row][c4 + 3] = v.w;
    }
    __syncthreads();
    const size_t tb = (size_t)(rt * 32 + kt) * 4096;
    for (int s = tid; s < 512; s += 256) {
        const int g = s >> 7, kk = (s >> 6) & 1, l = s & 63;
        const int row = g * 32 + (l & 31);
        const int k0 = kk * 16 + ((l >> 5) & 1) * 8;
        bf16x8 hv, lv;
        #pragma unroll
        for (int e = 0; e < 8; ++e) {
            const float f = Ls[row][k0 + e];
            const unsigned int u = __float_as_uint(f);
            const unsigned short h = (unsigned short)(u >> 16);   // truncate
            hv[e] = (short)h;
            lv[e] = (short)f2bf(f - bf2f(h));
        }
        *(bf16x8*)&dh[tb + s * 8] = hv;
        *(bf16x8*)&dl[tb + s * 8] = lv;
    }
}

// ---------------------------------------------------------------------------
// bf16x3 32x32x16 MFMA GEMM core. 128x128 tile, 4 waves (64x64 each), BK=32.
// A: fp32 row-major (lda=1024), converted to hi/lo bf16 during staging.
//    Staging is slot-aligned: thread t owns LDS fragment slots {t, t+256};
//    writes are 16B at byte slot*16 -> contiguous per wave (0 bank conflicts).
//    The fragment permutation lives in the per-thread GLOBAL read address.
// B: pre-packed hi/lo tiles, contiguous 16B staging writes (0 conflicts).
// acc += Ah*Bh + Ah*Bl + Al*Bh.
// LDS: Ah[0,8K) Al[8K,16K) Bh[16K,24K) Bl[24K,32K).
// XCD-chunked swizzle on 1-D grid (gridDim.x % 8 == 0).
// ---------------------------------------------------------------------------
#define GEMM32_CORE(Afp_, Bh_, Bl_, NNB)                                       \
    __shared__ __attribute__((aligned(16))) char smem[32768];                  \
    const int tid = threadIdx.x;                                               \
    const int lane = tid & 63, wid = tid >> 6;                                 \
    const int cpx = gridDim.x >> 3;                                            \
    const int wg = (blockIdx.x & 7) * cpx + (blockIdx.x >> 3);                 \
    const int bm = wg / (NNB), bn = wg % (NNB);                                \
    const int wrow = wid >> 1, wcol = wid & 1;                                 \
    /* A: slot s=(g*2+kk)*64+l -> row=g*32+(l&31), k0=kk*16+(l>>5)*8 */        \
    const int l_  = tid & 63;                                                  \
    const int kk_ = (tid >> 6) & 1;                                            \
    const int kc_ = kk_ * 16 + (l_ >> 5) * 8;                                  \
    const int row0_ = (tid >> 7) * 32 + (l_ & 31);        /* slot t   */       \
    const int row1_ = 64 + row0_;                          /* slot t+256 */    \
    const float* aptr0 = (Afp_) + (size_t)(bm * 128 + row0_) * 1024 + kc_;     \
    const float* aptr1 = (Afp_) + (size_t)(bm * 128 + row1_) * 1024 + kc_;     \
    /* B: 4 x 16B contiguous slots per thread */                               \
    const unsigned short* bsrc[4]; int boff[4];                                \
    _Pragma("unroll")                                                          \
    for (int p = 0; p < 4; ++p) {                                              \
        const int fb = p * 256 + tid;                                          \
        const int half = fb >> 9;           /* 0: hi buf, 1: lo buf */         \
        const int fi = fb & 511;                                               \
        bsrc[p] = (half ? (Bl_) : (Bh_)) + fi * 8;                             \
        boff[p] = 16384 + half * 8192 + fi * 16;                               \
    }                                                                          \
    const size_t btb = (size_t)bn * 32 * 4096;                                 \
    f32x16 acc[2][2] = {};                                                     \
    float4 sA0a, sA0b, sA1a, sA1b; float4 sB[4];                               \
    bf16x8 h0, lo0, h1, lo1;                                                   \
    sA0a = *(const float4*)(aptr0);                                            \
    sA0b = *(const float4*)(aptr0 + 4);                                        \
    sA1a = *(const float4*)(aptr1);                                            \
    sA1b = *(const float4*)(aptr1 + 4);                                        \
    _Pragma("unroll")                                                          \
    for (int p = 0; p < 4; ++p) sB[p] = *(const float4*)(bsrc[p] + btb);       \
    cvt8(sA0a, sA0b, h0, lo0);                                                 \
    cvt8(sA1a, sA1b, h1, lo1);                                                 \
    for (int kt = 0; kt < 32; ++kt) {                                          \
        __syncthreads();                                                       \
        *(bf16x8*)(smem + tid * 16) = h0;                                      \
        *(bf16x8*)(smem + 4096 + tid * 16) = h1;                               \
        *(bf16x8*)(smem + 8192 + tid * 16) = lo0;                              \
        *(bf16x8*)(smem + 12288 + tid * 16) = lo1;                             \
        _Pragma("unroll")                                                      \
        for (int p = 0; p < 4; ++p) *(float4*)(smem + boff[p]) = sB[p];        \
        __syncthreads();                                                       \
        if (kt + 1 < 32) {                                                     \
            sA0a = *(const float4*)(aptr0 + (kt + 1) * 32);                    \
            sA0b = *(const float4*)(aptr0 + (kt + 1) * 32 + 4);                \
            sA1a = *(const float4*)(aptr1 + (kt + 1) * 32);                    \
            sA1b = *(const float4*)(aptr1 + (kt + 1) * 32 + 4);                \
            _Pragma("unroll")                                                  \
            for (int p = 0; p < 4; ++p)                                        \
                sB[p] = *(const float4*)(bsrc[p] + btb + (size_t)(kt + 1) * 4096); \
        }                                                                      \
        _Pragma("unroll")                                                      \
        for (int kk = 0; kk < 2; ++kk) {                                       \
            bf16x8 fa[2], fal[2], fb2[2], fbl[2];                              \
            _Pragma("unroll")                                                  \
            for (int ti = 0; ti < 2; ++ti) {                                   \
                const int o = (((wrow * 2 + ti) * 2 + kk) << 10) + lane * 16;  \
                fa[ti]  = *(const bf16x8*)(smem + o);                          \
                fal[ti] = *(const bf16x8*)(smem + 8192 + o);                   \
            }                                                                  \
            _Pragma("unroll")                                                  \
            for (int tj = 0; tj < 2; ++tj) {                                   \
                const int o = (((wcol * 2 + tj) * 2 + kk) << 10) + lane * 16;  \
                fb2[tj] = *(const bf16x8*)(smem + 16384 + o);                  \
                fbl[tj] = *(const bf16x8*)(smem + 24576 + o);                  \
            }                                                                  \
            _Pragma("unroll")                                                  \
            for (int ti = 0; ti < 2; ++ti)                                     \
                _Pragma("unroll")                                              \
                for (int tj = 0; tj < 2; ++tj) {                               \
                    acc[ti][tj] = __builtin_amdgcn_mfma_f32_32x32x16_bf16(     \
                        fa[ti], fb2[tj], acc[ti][tj], 0, 0, 0);                \
                    acc[ti][tj] = __builtin_amdgcn_mfma_f32_32x32x16_bf16(     \
                        fa[ti], fbl[tj], acc[ti][tj], 0, 0, 0);                \
                    acc[ti][tj] = __builtin_amdgcn_mfma_f32_32x32x16_bf16(     \
                        fal[ti], fb2[tj], acc[ti][tj], 0, 0, 0);               \
                }                                                              \
        }                                                                      \
        if (kt + 1 < 32) {                                                     \
            cvt8(sA0a, sA0b, h0, lo0);                                         \
            cvt8(sA1a, sA1b, h1, lo1);                                         \
        }                                                                      \
    }

// K1: kqv GEMM (A = x fp32), scatter to Kt/Qt/Vt with mask (+1/8 on Q).
__global__ __launch_bounds__(256) void k_kqv_gemm(
    const float* __restrict__ x,
    const unsigned short* __restrict__ wh, const unsigned short* __restrict__ wl,
    const float* __restrict__ mask,
    float* __restrict__ Kt, float* __restrict__ Qt, float* __restrict__ Vt)
{
    GEMM32_CORE(x, wh, wl, 24)
    const int part = bn >> 3;
    #pragma unroll
    for (int ti = 0; ti < 2; ++ti) {
        #pragma unroll
        for (int tj = 0; tj < 2; ++tj) {
            const int col = (bn * 128 + wcol * 64 + tj * 32 + (lane & 31)) & 1023;
            const int h = col >> 6, d = col & 63;
            #pragma unroll
            for (int r = 0; r < 16; ++r) {
                const int row = bm * 128 + wrow * 64 + ti * 32
                              + (r & 3) + 8 * (r >> 2) + 4 * (lane >> 5);
                const int b = row >> 12, l = row & 4095;
                const float mk = mask[b * Ln + l];
                const size_t idx = ((size_t)(b * Hn + h) * Ln + l) * HDn + d;
                const float v = acc[ti][tj][r] * mk;
                if (part == 0)      Kt[idx] = v;
                else if (part == 1) Qt[idx] = v * 0.125f;
                else                Vt[idx] = v;
            }
        }
    }
}

// K8: out GEMM (A = attn fp32) + bias.
__global__ __launch_bounds__(256) void k_out_gemm(
    const float* __restrict__ attn,
    const unsigned short* __restrict__ woh, const unsigned short* __restrict__ wol,
    const float* __restrict__ bias, float* __restrict__ out)
{
    GEMM32_CORE(attn, woh, wol, 8)
    #pragma unroll
    for (int ti = 0; ti < 2; ++ti) {
        #pragma unroll
        for (int tj = 0; tj < 2; ++tj) {
            const int col = bn * 128 + wcol * 64 + tj * 32 + (lane & 31);
            const float bb = bias[col];
            #pragma unroll
            for (int r = 0; r < 16; ++r) {
                const int row = bm * 128 + wrow * 64 + ti * 32
                              + (r & 3) + 8 * (r >> 2) + 4 * (lane >> 5);
                out[(size_t)row * Dn + col] = acc[ti][tj][r] + bb;
            }
        }
    }
}

// ---------------------------------------------------------------------------
// K2: landmark means + zero gmax.
// ---------------------------------------------------------------------------
__global__ __launch_bounds__(64) void k_landmarks(
    const float* __restrict__ Kt, const float* __restrict__ Qt,
    const float* __restrict__ mask,
    float* __restrict__ klm, float* __restrict__ qlm, int* __restrict__ gmax)
{
    const int blk = blockIdx.x;
    const int m = blk & 63, bh = blk >> 6, b = bh >> 4;
    const int d = threadIdx.x;
    if (blk == 0 && d < 2) gmax[d] = 0;
    float mv = mask[b * Ln + m * SEGn + d];
    #pragma unroll
    for (int off = 32; off; off >>= 1) mv += __shfl_down(mv, off);
    const float denom = __shfl(mv, 0) + 1e-8f;
    const float* kp = Kt + ((size_t)bh * Ln + m * SEGn) * HDn + d;
    const float* qp = Qt + ((size_t)bh * Ln + m * SEGn) * HDn + d;
    float sk = 0.f, sq = 0.f;
    for (int j = 0; j < SEGn; ++j) {
        sk += kp[(size_t)j * HDn];
        sq += qp[(size_t)j * HDn];
    }
    klm[((size_t)bh * NLn + m) * HDn + d] = sk / denom;
    qlm[((size_t)bh * NLn + m) * HDn + d] = sq / denom;
}

// ---------------------------------------------------------------------------
// K3: s2 = softmax(q_lm @ k_lm^T) + global |row|/|col| sum maxes.
// ---------------------------------------------------------------------------
__global__ __launch_bounds__(64) void k_s2(
    const float* __restrict__ qlm, const float* __restrict__ klm,
    float* __restrict__ s2, int* __restrict__ gmax)
{
    const int bh = blockIdx.x;
    __shared__ float ql[64][65];
    __shared__ float kl[64][65];
    __shared__ float sr[64][65];
    const int t = threadIdx.x;
    for (int idx = t; idx < 4096; idx += 64) {
        ql[idx >> 6][idx & 63] = qlm[(size_t)bh * 4096 + idx];
        kl[idx >> 6][idx & 63] = klm[(size_t)bh * 4096 + idx];
    }
    __syncthreads();
    float mx = -1e30f;
    for (int mp = 0; mp < 64; ++mp) {
        float s = 0.f;
        #pragma unroll 8
        for (int d2 = 0; d2 < 64; ++d2) s = fmaf(ql[t][d2], kl[mp][d2], s);
        sr[t][mp] = s;
        mx = fmaxf(mx, s);
    }
    float sum = 0.f;
    for (int mp = 0; mp < 64; ++mp) {
        const float e = expf(sr[t][mp] - mx);
        sr[t][mp] = e;
        sum += e;
    }
    const float inv = 1.f / sum;
    float rs = 0.f;
    for (int mp = 0; mp < 64; ++mp) {
        const float v = sr[t][mp] * inv;
        sr[t][mp] = v;
        s2[(size_t)bh * 4096 + t * 64 + mp] = v;
        rs += fabsf(v);
    }
    __syncthreads();
    float cs = 0.f;
    for (int mm = 0; mm < 64; ++mm) cs += fabsf(sr[mm][t]);
    float rmax = rs, cmax = cs;
    #pragma unroll
    for (int off = 32; off; off >>= 1) {
        rmax = fmaxf(rmax, __shfl_down(rmax, off));
        cmax = fmaxf(cmax, __shfl_down(cmax, off));
    }
    if (t == 0) {
        atomicMax(&gmax[0], __float_as_int(rmax));
        atomicMax(&gmax[1], __float_as_int(cmax));
    }
}

// ---------------------------------------------------------------------------
// 64x64 fp32 matmul helper: C = scl * A @ (SUB ? dg*I - B : B).
// ---------------------------------------------------------------------------
template<int SUB>
__device__ __forceinline__ void mm64g(
    float* C, int ldc, const float* Ag, int lda,
    const float* Bm, int ldb, float dg, float scl)
{
    const int tid = threadIdx.x;
    const int tx = tid & 15, ty = tid >> 4;
    const int i0 = ty << 2, j0 = tx << 2;
    float acc[4][4] = {};
    for (int k = 0; k < 64; ++k) {
        float a[4], bb[4];
        #pragma unroll
        for (int i = 0; i < 4; ++i) a[i] = Ag[(size_t)(i0 + i) * lda + k];
        #pragma unroll
        for (int j = 0; j < 4; ++j) {
            float v = Bm[(size_t)k * ldb + j0 + j];
            if (SUB) v = ((k == j0 + j) ? dg : 0.0f) - v;
            bb[j] = v;
        }
        #pragma unroll
        for (int i = 0; i < 4; ++i)
            #pragma unroll
            for (int j = 0; j < 4; ++j) acc[i][j] = fmaf(a[i], bb[j], acc[i][j]);
    }
    __syncthreads();
    #pragma unroll
    for (int i = 0; i < 4; ++i)
        #pragma unroll
        for (int j = 0; j < 4; ++j) C[(size_t)(i0 + i) * ldc + j0 + j] = scl * acc[i][j];
    __syncthreads();
}

// ---------------------------------------------------------------------------
// K4: Moore-Penrose pinv, 6 Newton-Schulz iterations.
// ---------------------------------------------------------------------------
__global__ __launch_bounds__(256) void k_pinv(
    const float* __restrict__ s2, const int* __restrict__ gmax,
    float* __restrict__ zout)
{
    __shared__ float Zb[64][65];
    __shared__ float XZ[64][65];
    __shared__ float Tb[64][64];
    const int bh = blockIdx.x;
    const int tid = threadIdx.x;
    const float* X = s2 + (size_t)bh * 4096;
    const float scale = 1.0f / (__int_as_float(gmax[0]) * __int_as_float(gmax[1]));
    for (int idx = tid; idx < 4096; idx += 256) {
        const int i = idx >> 6, j = idx & 63;
        Zb[i][j] = X[j * 64 + i] * scale;
    }
    __syncthreads();
    for (int it = 0; it < 6; ++it) {
        mm64g<0>(&XZ[0][0], 65, X, 64, &Zb[0][0], 65, 0.f, 1.f);
        mm64g<1>(&Tb[0][0], 64, &XZ[0][0], 65, &XZ[0][0], 65, 7.f, 1.f);
        mm64g<1>(&Tb[0][0], 64, &XZ[0][0], 65, &Tb[0][0], 64, 15.f, 1.f);
        mm64g<1>(&Zb[0][0], 65, &Zb[0][0], 65, &Tb[0][0], 64, 13.f, 0.25f);
    }
    for (int idx = tid; idx < 4096; idx += 256)
        zout[(size_t)bh * 4096 + idx] = Zb[idx >> 6][idx & 63];
}

// ---------------------------------------------------------------------------
// K5a: s3v partial over 512-row chunk, online softmax. grid (BH, NCH).
// ---------------------------------------------------------------------------
__global__ __launch_bounds__(256) void k_s3v_part(
    const float* __restrict__ qlm, const float* __restrict__ Kt,
    const float* __restrict__ Vt, const float* __restrict__ mask,
    float* __restrict__ Opart, float* __restrict__ mpart, float* __restrict__ spart)
{
    __shared__ float Ql[64][65];
    __shared__ float Ks[64][65];
    __shared__ float Vs[64][64];
    __shared__ float S[64][65];
    __shared__ float rowmax[64], rowsum[64], fac[64], mrow[64];
    const int bh = blockIdx.x, ch = blockIdx.y;
    const int b = bh >> 4;
    const int tid = threadIdx.x;
    const int tx = tid & 15, ty = tid >> 4;
    const int i0 = ty << 2, j0 = tx << 2;
    for (int idx = tid; idx < 4096; idx += 256)
        Ql[idx >> 6][idx & 63] = qlm[(size_t)bh * 4096 + idx];
    if (tid < 64) { rowmax[tid] = -1e30f; rowsum[tid] = 0.f; }
    float acc[4][4] = {};
    const int t0beg = ch * (Ln / NCH), t0end = t0beg + (Ln / NCH);
    for (int t0 = t0beg; t0 < t0end; t0 += 64) {
        __syncthreads();
        for (int idx = tid; idx < 4096; idx += 256) {
            const int r = idx >> 6, c2 = idx & 63;
            Ks[r][c2] = Kt[((size_t)bh * Ln + t0 + r) * HDn + c2];
            Vs[r][c2] = Vt[((size_t)bh * Ln + t0 + r) * HDn + c2];
        }
        if (tid < 64) mrow[tid] = mask[b * Ln + t0 + tid];
        __syncthreads();
        float sacc[4][4] = {};
        for (int k = 0; k < 64; ++k) {
            float a[4], bb4[4];
            #pragma unroll
            for (int i = 0; i < 4; ++i) a[i] = Ql[i0 + i][k];
            #pragma unroll
            for (int j = 0; j < 4; ++j) bb4[j] = Ks[j0 + j][k];
            #pragma unroll
            for (int i = 0; i < 4; ++i)
                #pragma unroll
                for (int j = 0; j < 4; ++j) sacc[i][j] = fmaf(a[i], bb4[j], sacc[i][j]);
        }
        #pragma unroll
        for (int i = 0; i < 4; ++i)
            #pragma unroll
            for (int j = 0; j < 4; ++j)
                S[i0 + i][j0 + j] = sacc[i][j] + (1.f - mrow[j0 + j]) * NEG_BIG;
        __syncthreads();
        if (tid < 64) {
            const int m = tid;
            float mx = -1e30f;
            for (int j = 0; j < 64; ++j) mx = fmaxf(mx, S[m][j]);
            const float nm = fmaxf(rowmax[m], mx);
            const float f = expf(rowmax[m] - nm);
            float ps = 0.f;
            for (int j = 0; j < 64; ++j) {
                const float e = expf(S[m][j] - nm);
                S[m][j] = e;
                ps += e;
            }
            rowsum[m] = rowsum[m] * f + ps;
            rowmax[m] = nm;
            fac[m] = f;
        }
        __syncthreads();
        #pragma unroll
        for (int i = 0; i < 4; ++i) {
            const float f = fac[i0 + i];
            #pragma unroll
            for (int j = 0; j < 4; ++j) acc[i][j] *= f;
        }
        for (int k = 0; k < 64; ++k) {
            float a[4], bb4[4];
            #pragma unroll
            for (int i = 0; i < 4; ++i) a[i] = S[i0 + i][k];
            #pragma unroll
            for (int j = 0; j < 4; ++j) bb4[j] = Vs[k][j0 + j];
            #pragma unroll
            for (int i = 0; i < 4; ++i)
                #pragma unroll
                for (int j = 0; j < 4; ++j) acc[i][j] = fmaf(a[i], bb4[j], acc[i][j]);
        }
    }
    const size_t ob = (size_t)(bh * NCH + ch) * 4096;
    #pragma unroll
    for (int i = 0; i < 4; ++i)
        #pragma unroll
        for (int j = 0; j < 4; ++j)
            Opart[ob + (i0 + i) * 64 + j0 + j] = acc[i][j];
    if (tid < 64) {
        mpart[(bh * NCH + ch) * 64 + tid] = rowmax[tid];
        spart[(bh * NCH + ch) * 64 + tid] = rowsum[tid];
    }
}

// K5b: merge chunks.
__global__ __launch_bounds__(256) void k_s3v_merge(
    const float* __restrict__ Opart, const float* __restrict__ mpart,
    const float* __restrict__ spart, float* __restrict__ s3v)
{
    const int bh = blockIdx.x, tid = threadIdx.x;
    const int r = tid >> 2, c0 = (tid & 3) * 16;
    float e[NCH];
    float M = -1e30f;
    #pragma unroll
    for (int c = 0; c < NCH; ++c) {
        e[c] = mpart[(bh * NCH + c) * 64 + r];
        M = fmaxf(M, e[c]);
    }
    float S = 0.f;
    #pragma unroll
    for (int c = 0; c < NCH; ++c) {
        e[c] = expf(e[c] - M);
        S += spart[(bh * NCH + c) * 64 + r] * e[c];
    }
    const float invS = 1.f / S;
    for (int col = c0; col < c0 + 16; ++col) {
        float o = 0.f;
        #pragma unroll
        for (int c = 0; c < NCH; ++c)
            o += Opart[(size_t)(bh * NCH + c) * 4096 + r * 64 + col] * e[c];
        s3v[(size_t)bh * 4096 + r * 64 + col] = o * invS;
    }
}

// ---------------------------------------------------------------------------
// K6: W = z_star @ s3v (per bh, 64x64).
// ---------------------------------------------------------------------------
__global__ __launch_bounds__(256) void k_zmul(
    const float* __restrict__ Zs, const float* __restrict__ s3v,
    float* __restrict__ Wm)
{
    __shared__ float Ab[64][65];
    __shared__ float Bb[64][64];
    const int bh = blockIdx.x;
    const int tid = threadIdx.x;
    for (int idx = tid; idx < 4096; idx += 256) {
        Ab[idx >> 6][idx & 63] = Zs[(size_t)bh * 4096 + idx];
        Bb[idx >> 6][idx & 63] = s3v[(size_t)bh * 4096 + idx];
    }
    __syncthreads();
    const int tx = tid & 15, ty = tid >> 4;
    const int i0 = ty << 2, j0 = tx << 2;
    float acc[4][4] = {};
    for (int k = 0; k < 64; ++k) {
        float a[4], bb4[4];
        #pragma unroll
        for (int i = 0; i < 4; ++i) a[i] = Ab[i0 + i][k];
        #pragma unroll
        for (int j = 0; j < 4; ++j) bb4[j] = Bb[k][j0 + j];
        #pragma unroll
        for (int i = 0; i < 4; ++i)
            #pragma unroll
            for (int j = 0; j < 4; ++j) acc[i][j] = fmaf(a[i], bb4[j], acc[i][j]);
    }
    #pragma unroll
    for (int i = 0; i < 4; ++i)
        #pragma unroll
        for (int j = 0; j < 4; ++j)
            Wm[(size_t)bh * 4096 + (i0 + i) * 64 + j0 + j] = acc[i][j];
}

// ---------------------------------------------------------------------------
// K7: out_attn = softmax(q @ k_lm^T) @ W -> fp32 attn [B][L][H*HD].
// ---------------------------------------------------------------------------
__global__ __launch_bounds__(256) void k_attn_out(
    const float* __restrict__ Qt, const float* __restrict__ klm,
    const float* __restrict__ Wm, float* __restrict__ attn)
{
    const int lt = blockIdx.x;
    const int bh = blockIdx.y;
    const int b = bh >> 4, h = bh & 15;
    __shared__ float Qs[64][65];
    __shared__ float Ks[64][65];
    __shared__ float Ws[64][64];
    __shared__ float S[64][65];
    __shared__ float rsum[64];
    const int tid = threadIdx.x;
    const int tx = tid & 15, ty = tid >> 4;
    const int i0 = ty << 2, j0 = tx << 2;
    for (int idx = tid; idx < 4096; idx += 256) {
        const int r = idx >> 6, c2 = idx & 63;
        Qs[r][c2] = Qt[((size_t)bh * Ln + lt * 64 + r) * HDn + c2];
        Ks[r][c2] = klm[(size_t)bh * 4096 + idx];
        Ws[r][c2] = Wm[(size_t)bh * 4096 + idx];
    }
    __syncthreads();
    float sacc[4][4] = {};
    for (int k = 0; k < 64; ++k) {
        float a[4], bb4[4];
        #pragma unroll
        for (int i = 0; i < 4; ++i) a[i] = Qs[i0 + i][k];
        #pragma unroll
        for (int j = 0; j < 4; ++j) bb4[j] = Ks[j0 + j][k];
        #pragma unroll
        for (int i = 0; i < 4; ++i)
            #pragma unroll
            for (int j = 0; j < 4; ++j) sacc[i][j] = fmaf(a[i], bb4[j], sacc[i][j]);
    }
    #pragma unroll
    for (int i = 0; i < 4; ++i)
        #pragma unroll
        for (int j = 0; j < 4; ++j) S[i0 + i][j0 + j] = sacc[i][j];
    __syncthreads();
    if (tid < 64) {
        float mx = -1e30f;
        for (int j = 0; j < 64; ++j) mx = fmaxf(mx, S[tid][j]);
        float ps = 0.f;
        for (int j = 0; j < 64; ++j) {
            const float e = expf(S[tid][j] - mx);
            S[tid][j] = e;
            ps += e;
        }
        rsum[tid] = ps;
    }
    __syncthreads();
    float acc[4][4] = {};
    for (int k = 0; k < 64; ++k) {
        float a[4], bb4[4];
        #pragma unroll
        for (int i = 0; i < 4; ++i) a[i] = S[i0 + i][k];
        #pragma unroll
        for (int j = 0; j < 4; ++j) bb4[j] = Ws[k][j0 + j];
        #pragma unroll
        for (int i = 0; i < 4; ++i)
            #pragma unroll
            for (int j = 0; j < 4; ++j) acc[i][j] = fmaf(a[i], bb4[j], acc[i][j]);
    }
    #pragma unroll
    for (int i = 0; i < 4; ++i) {
        const float inv = 1.f / rsum[i0 + i];
        float4 v;
        v.x = acc[i][0] * inv; v.y = acc[i][1] * inv;
        v.z = acc[i][2] * inv; v.w = acc[i][3] * inv;
        const size_t row = (size_t)(b * Ln + lt * 64 + i0 + i);
        *(float4*)&attn[row * Dn + h * 64 + j0] = v;
    }
}

// ---------------------------------------------------------------------------
extern "C" void kernel_launch(void* const* d_in, const int* in_sizes, int n_in,
                              void* d_out, int out_size, void* d_ws, size_t ws_size,
                              hipStream_t stream)
{
    (void)in_sizes; (void)n_in; (void)out_size; (void)ws_size;
    const float* x    = (const float*)d_in[0];
    const float* mask = (const float*)d_in[1];
    const float* wkqv = (const float*)d_in[2];
    const float* wout = (const float*)d_in[3];
    const float* bout = (const float*)d_in[4];
    float* out = (float*)d_out;
    float* ws  = (float*)d_ws;

    float* Kt   = ws + OFF_KT;
    float* Qt   = ws + OFF_QT;
    float* Vt   = ws + OFF_VT;
    float* qlm  = ws + OFF_QLM;
    float* klm  = ws + OFF_KLM;
    float* s2   = ws + OFF_S2;
    float* zst  = ws + OFF_Z;
    float* s3v  = ws + OFF_S3V;
    float* Wm   = ws + OFF_WM;
    int*   gmax = (int*)(ws + OFF_GM);
    float* mpart = ws + OFF_PM;
    float* spart = ws + OFF_PS;
    float* Opart = ws + OFF_PO;                        // alias wh/wl (dead)
    unsigned short* wh  = (unsigned short*)(ws + OFF_WH);
    unsigned short* wl  = (unsigned short*)(ws + OFF_WL);
    unsigned short* woh = (unsigned short*)(ws + OFF_WOH);  // alias Vt (dead)
    unsigned short* wol = (unsigned short*)(ws + OFF_WOL);
    float* attn = ws + OFF_KT;                         // alias Kt (dead)

    hipMemsetAsync(gmax, 0, 2 * sizeof(int), stream);
    k_pack<<<dim3(24, 32), 256, 0, stream>>>(wkqv, wh, wl);
    k_kqv_gemm<<<128 * 24, 256, 0, stream>>>(x, wh, wl, mask, Kt, Qt, Vt);
    k_landmarks<<<BHn * NLn, 64, 0, stream>>>(Kt, Qt, mask, klm, qlm, gmax);
    k_s2<<<BHn, 64, 0, stream>>>(qlm, klm, s2, gmax);
    k_pinv<<<BHn, 256, 0, stream>>>(s2, gmax, zst);
    k_s3v_part<<<dim3(BHn, NCH), 256, 0, stream>>>(qlm, Kt, Vt, mask, Opart, mpart, spart);
    k_pack<<<dim3(8, 32), 256, 0, stream>>>(wout, woh, wol);
    k_s3v_merge<<<BHn, 256, 0, stream>>>(Opart, mpart, spart, s3v);
    k_zmul<<<BHn, 256, 0, stream>>>(zst, s3v, Wm);
    k_attn_out<<<dim3(Ln / 64, BHn), 256, 0, stream>>>(Qt, klm, Wm, attn);
    k_out_gemm<<<128 * 8, 256, 0, stream>>>(attn, woh, wol, bout, out);
}